// Round 1
// baseline (10902.831 us; speedup 1.0000x reference)
//
#include <hip/hip_runtime.h>
#include <hip/hip_bf16.h>

#define N_NODES 100000
#define N_EDGES 3200000
#define DFEAT 256
#define UNITS 256

// ---------------------------------------------------------------------------
// Kernel 1: edge scatter  tmp[r,:] += val_e * x[c,:]
// One wave (64 lanes) per edge; each lane handles 4 consecutive features via
// float4 (64*4 = 256). Gather of x[c] is fully coalesced (1 KB/wave).
// ---------------------------------------------------------------------------
__global__ __launch_bounds__(256) void scatter_edges(
    const int* __restrict__ erow, const int* __restrict__ ecol,
    const float* __restrict__ eval, const float* __restrict__ x,
    float* __restrict__ tmp, int E)
{
    const int wave = threadIdx.x >> 6;
    const int lane = threadIdx.x & 63;
    const int e = blockIdx.x * 4 + wave;
    if (e >= E) return;

    const int r = erow[e];
    const int c = ecol[e];
    const float v = eval[e];

    const float4* __restrict__ x4 = (const float4*)x;
    float4 xv = x4[(size_t)c * 64 + lane];

    float* dst = &tmp[(size_t)r * 256 + lane * 4];
    atomicAdd(dst + 0, v * xv.x);
    atomicAdd(dst + 1, v * xv.y);
    atomicAdd(dst + 2, v * xv.z);
    atomicAdd(dst + 3, v * xv.w);
}

// ---------------------------------------------------------------------------
// Kernel 2: out = relu(tmp @ W + bias)    (M x 256) @ (256 x 256)
// fp32 vector GEMM (no fp32 MFMA on CDNA4). 64x64 block tile, 256 threads,
// 4x4 micro-tile per thread, BK=16 LDS staging, float4 LDS reads.
// LDS rows padded to 68 floats (16B-aligned, breaks 4-way store conflicts).
// ---------------------------------------------------------------------------
#define BM 64
#define BN 64
#define BK 16
#define LDS_STRIDE 68

__global__ __launch_bounds__(256) void gemm_bias_relu(
    const float* __restrict__ A,     // tmp: M x 256
    const float* __restrict__ B,     // weight: 256 x 256
    const float* __restrict__ bias,
    float* __restrict__ C,           // out: M x 256
    int M)
{
    __shared__ float As[BK * LDS_STRIDE];  // As[k][m]  (A transposed into LDS)
    __shared__ float Bs[BK * LDS_STRIDE];  // Bs[k][n]

    const int tid = threadIdx.x;
    const int tx = tid % 16;              // n-tile coord
    const int ty = tid / 16;              // m-tile coord
    const int block_m = blockIdx.x * BM;
    const int block_n = blockIdx.y * BN;

    // staging coords
    const int a_m = tid / 4;              // 0..63
    const int a_k = (tid % 4) * 4;        // 0,4,8,12
    const int b_k = tid / 16;             // 0..15
    const int b_n = (tid % 16) * 4;       // 0..60

    float acc[4][4] = {};

    for (int k0 = 0; k0 < DFEAT; k0 += BK) {
        // stage A tile (transpose to As[k][m])
        const int gm = block_m + a_m;
        float4 av = make_float4(0.f, 0.f, 0.f, 0.f);
        if (gm < M)
            av = *(const float4*)&A[(size_t)gm * DFEAT + k0 + a_k];
        As[(a_k + 0) * LDS_STRIDE + a_m] = av.x;
        As[(a_k + 1) * LDS_STRIDE + a_m] = av.y;
        As[(a_k + 2) * LDS_STRIDE + a_m] = av.z;
        As[(a_k + 3) * LDS_STRIDE + a_m] = av.w;

        // stage B tile
        float4 bv = *(const float4*)&B[(size_t)(k0 + b_k) * UNITS + block_n + b_n];
        *(float4*)&Bs[b_k * LDS_STRIDE + b_n] = bv;

        __syncthreads();

#pragma unroll
        for (int kk = 0; kk < BK; ++kk) {
            float4 a = *(const float4*)&As[kk * LDS_STRIDE + ty * 4];
            float4 b = *(const float4*)&Bs[kk * LDS_STRIDE + tx * 4];
            const float ar[4] = {a.x, a.y, a.z, a.w};
            const float br[4] = {b.x, b.y, b.z, b.w};
#pragma unroll
            for (int i = 0; i < 4; ++i)
#pragma unroll
                for (int j = 0; j < 4; ++j)
                    acc[i][j] = fmaf(ar[i], br[j], acc[i][j]);
        }
        __syncthreads();
    }

    // epilogue: bias + relu, float4 stores
    float4 bb = *(const float4*)&bias[block_n + tx * 4];
    const float bias_r[4] = {bb.x, bb.y, bb.z, bb.w};
#pragma unroll
    for (int i = 0; i < 4; ++i) {
        const int row = block_m + ty * 4 + i;
        if (row < M) {
            float4 o;
            o.x = fmaxf(acc[i][0] + bias_r[0], 0.f);
            o.y = fmaxf(acc[i][1] + bias_r[1], 0.f);
            o.z = fmaxf(acc[i][2] + bias_r[2], 0.f);
            o.w = fmaxf(acc[i][3] + bias_r[3], 0.f);
            *(float4*)&C[(size_t)row * UNITS + block_n + tx * 4] = o;
        }
    }
}

extern "C" void kernel_launch(void* const* d_in, const int* in_sizes, int n_in,
                              void* d_out, int out_size, void* d_ws, size_t ws_size,
                              hipStream_t stream) {
    const int*   erow = (const int*)d_in[0];
    const int*   ecol = (const int*)d_in[1];
    const float* eval = (const float*)d_in[2];
    const float* x    = (const float*)d_in[3];
    const float* w    = (const float*)d_in[4];
    const float* bias = (const float*)d_in[5];
    float* out = (float*)d_out;
    float* tmp = (float*)d_ws;   // N_NODES x 256 fp32 = 102.4 MB

    // zero the scatter accumulator (d_ws is poisoned 0xAA before every call)
    hipMemsetAsync(tmp, 0, (size_t)N_NODES * UNITS * sizeof(float), stream);

    // tmp = A_coo @ X
    scatter_edges<<<N_EDGES / 4, 256, 0, stream>>>(erow, ecol, eval, x, tmp, N_EDGES);

    // out = relu(tmp @ W + bias)
    dim3 grid((N_NODES + BM - 1) / BM, UNITS / BN);
    gemm_bias_relu<<<grid, 256, 0, stream>>>(tmp, w, bias, out, N_NODES);
}

// Round 2
// 1176.428 us; speedup vs baseline: 9.2677x; 9.2677x over previous
//
#include <hip/hip_runtime.h>
#include <hip/hip_bf16.h>

#define N_NODES 100000
#define N_EDGES 3200000
#define DFEAT 256
#define UNITS 256

#define CHUNK 1024
#define NCHUNKS ((N_NODES + CHUNK - 1) / CHUNK)   // 98

// ---------------------------------------------------------------------------
// CSR build step 1: per-row edge counts (int atomics — fast, unlike fp32)
// ---------------------------------------------------------------------------
__global__ __launch_bounds__(256) void hist_rows(const int* __restrict__ erow,
                                                 int* __restrict__ cnt) {
    int e = blockIdx.x * 256 + threadIdx.x;
    if (e < N_EDGES) atomicAdd(&cnt[erow[e]], 1);
}

// ---------------------------------------------------------------------------
// CSR build step 2a: per-chunk sums (98 chunks of 1024 counts)
// ---------------------------------------------------------------------------
__global__ __launch_bounds__(256) void chunk_sums_k(const int* __restrict__ cnt,
                                                    int* __restrict__ csum) {
    __shared__ int red[256];
    int base = blockIdx.x * CHUNK;
    int s = 0;
    for (int i = threadIdx.x; i < CHUNK; i += 256) {
        int idx = base + i;
        s += (idx < N_NODES) ? cnt[idx] : 0;
    }
    red[threadIdx.x] = s;
    __syncthreads();
    for (int off = 128; off > 0; off >>= 1) {
        if (threadIdx.x < off) red[threadIdx.x] += red[threadIdx.x + off];
        __syncthreads();
    }
    if (threadIdx.x == 0) csum[blockIdx.x] = red[0];
}

// ---------------------------------------------------------------------------
// CSR build step 2b: serial exclusive scan of the 98 chunk sums (trivial)
// ---------------------------------------------------------------------------
__global__ void scan_chunk_sums(int* csum) {
    if (threadIdx.x == 0) {
        int run = 0;
        for (int i = 0; i < NCHUNKS; ++i) { int t = csum[i]; csum[i] = run; run += t; }
    }
}

// ---------------------------------------------------------------------------
// CSR build step 2c: per-chunk exclusive scan + chunk offset -> row_ptr, cursor
// ---------------------------------------------------------------------------
__global__ __launch_bounds__(256) void scan_final(const int* __restrict__ cnt,
                                                  const int* __restrict__ csum,
                                                  int* __restrict__ row_ptr,
                                                  int* __restrict__ cursor) {
    __shared__ int tsum[256];
    const int tid = threadIdx.x;
    int base = blockIdx.x * CHUNK + tid * 4;
    int v[4];
#pragma unroll
    for (int j = 0; j < 4; ++j) {
        int idx = base + j;
        v[j] = (idx < N_NODES) ? cnt[idx] : 0;
    }
    int local = v[0] + v[1] + v[2] + v[3];
    tsum[tid] = local;
    __syncthreads();
    // inclusive Hillis-Steele scan over 256 thread sums
    for (int off = 1; off < 256; off <<= 1) {
        int t = 0;
        if (tid >= off) t = tsum[tid - off];
        __syncthreads();
        if (tid >= off) tsum[tid] += t;
        __syncthreads();
    }
    int prefix = csum[blockIdx.x] + tsum[tid] - local;   // exclusive prefix
#pragma unroll
    for (int j = 0; j < 4; ++j) {
        int idx = base + j;
        if (idx < N_NODES) { row_ptr[idx] = prefix; cursor[idx] = prefix; }
        prefix += v[j];
    }
}

// ---------------------------------------------------------------------------
// CSR build step 3: scatter (col, val) into row-grouped slots (int atomics)
// ---------------------------------------------------------------------------
__global__ __launch_bounds__(256) void fill_csr(const int* __restrict__ erow,
                                                const int* __restrict__ ecol,
                                                const float* __restrict__ eval,
                                                int* __restrict__ cursor,
                                                int2* __restrict__ col_val) {
    int e = blockIdx.x * 256 + threadIdx.x;
    if (e >= N_EDGES) return;
    int r = erow[e];
    int pos = atomicAdd(&cursor[r], 1);
    col_val[pos] = make_int2(ecol[e], __float_as_int(eval[e]));
}

// ---------------------------------------------------------------------------
// Aggregate: one wave per row. tmp[row,:] = sum_e val_e * x[col_e,:]
// Each lane holds float4 of the 256-wide row. Zero float atomics; each
// output row written exactly once (zero-degree rows write zeros).
// ---------------------------------------------------------------------------
__global__ __launch_bounds__(256) void gather_rows(const int* __restrict__ row_ptr,
                                                   const int* __restrict__ cnt,
                                                   const int2* __restrict__ col_val,
                                                   const float* __restrict__ x,
                                                   float* __restrict__ tmp) {
    const int row = blockIdx.x * 4 + (threadIdx.x >> 6);
    if (row >= N_NODES) return;
    const int lane = threadIdx.x & 63;
    const int start = row_ptr[row];
    const int deg = cnt[row];
    const int2* __restrict__ cv = col_val + start;
    const float4* __restrict__ x4 = (const float4*)x;

    float4 acc = make_float4(0.f, 0.f, 0.f, 0.f);
    int i = 0;
    for (; i + 1 < deg; i += 2) {      // unroll x2 for ILP on the gathers
        int2 p0 = cv[i];
        int2 p1 = cv[i + 1];
        float4 g0 = x4[(size_t)p0.x * 64 + lane];
        float4 g1 = x4[(size_t)p1.x * 64 + lane];
        float v0 = __int_as_float(p0.y);
        float v1 = __int_as_float(p1.y);
        acc.x = fmaf(v0, g0.x, acc.x);
        acc.y = fmaf(v0, g0.y, acc.y);
        acc.z = fmaf(v0, g0.z, acc.z);
        acc.w = fmaf(v0, g0.w, acc.w);
        acc.x = fmaf(v1, g1.x, acc.x);
        acc.y = fmaf(v1, g1.y, acc.y);
        acc.z = fmaf(v1, g1.z, acc.z);
        acc.w = fmaf(v1, g1.w, acc.w);
    }
    if (i < deg) {
        int2 p0 = cv[i];
        float4 g0 = x4[(size_t)p0.x * 64 + lane];
        float v0 = __int_as_float(p0.y);
        acc.x = fmaf(v0, g0.x, acc.x);
        acc.y = fmaf(v0, g0.y, acc.y);
        acc.z = fmaf(v0, g0.z, acc.z);
        acc.w = fmaf(v0, g0.w, acc.w);
    }
    ((float4*)tmp)[(size_t)row * 64 + lane] = acc;
}

// ---------------------------------------------------------------------------
// out = relu(tmp @ W + bias)    (M x 256) @ (256 x 256), fp32 vector GEMM
// ---------------------------------------------------------------------------
#define BM 64
#define BN 64
#define BK 16
#define LDS_STRIDE 68

__global__ __launch_bounds__(256) void gemm_bias_relu(
    const float* __restrict__ A, const float* __restrict__ B,
    const float* __restrict__ bias, float* __restrict__ C, int M)
{
    __shared__ float As[BK * LDS_STRIDE];  // As[k][m]
    __shared__ float Bs[BK * LDS_STRIDE];  // Bs[k][n]

    const int tid = threadIdx.x;
    const int tx = tid % 16;
    const int ty = tid / 16;
    const int block_m = blockIdx.x * BM;
    const int block_n = blockIdx.y * BN;

    const int a_m = tid / 4;
    const int a_k = (tid % 4) * 4;
    const int b_k = tid / 16;
    const int b_n = (tid % 16) * 4;

    float acc[4][4] = {};

    for (int k0 = 0; k0 < DFEAT; k0 += BK) {
        const int gm = block_m + a_m;
        float4 av = make_float4(0.f, 0.f, 0.f, 0.f);
        if (gm < M)
            av = *(const float4*)&A[(size_t)gm * DFEAT + k0 + a_k];
        As[(a_k + 0) * LDS_STRIDE + a_m] = av.x;
        As[(a_k + 1) * LDS_STRIDE + a_m] = av.y;
        As[(a_k + 2) * LDS_STRIDE + a_m] = av.z;
        As[(a_k + 3) * LDS_STRIDE + a_m] = av.w;

        float4 bv = *(const float4*)&B[(size_t)(k0 + b_k) * UNITS + block_n + b_n];
        *(float4*)&Bs[b_k * LDS_STRIDE + b_n] = bv;

        __syncthreads();

#pragma unroll
        for (int kk = 0; kk < BK; ++kk) {
            float4 a = *(const float4*)&As[kk * LDS_STRIDE + ty * 4];
            float4 b = *(const float4*)&Bs[kk * LDS_STRIDE + tx * 4];
            const float ar[4] = {a.x, a.y, a.z, a.w};
            const float br[4] = {b.x, b.y, b.z, b.w};
#pragma unroll
            for (int i = 0; i < 4; ++i)
#pragma unroll
                for (int j = 0; j < 4; ++j)
                    acc[i][j] = fmaf(ar[i], br[j], acc[i][j]);
        }
        __syncthreads();
    }

    float4 bb = *(const float4*)&bias[block_n + tx * 4];
    const float bias_r[4] = {bb.x, bb.y, bb.z, bb.w};
#pragma unroll
    for (int i = 0; i < 4; ++i) {
        const int row = block_m + ty * 4 + i;
        if (row < M) {
            float4 o;
            o.x = fmaxf(acc[i][0] + bias_r[0], 0.f);
            o.y = fmaxf(acc[i][1] + bias_r[1], 0.f);
            o.z = fmaxf(acc[i][2] + bias_r[2], 0.f);
            o.w = fmaxf(acc[i][3] + bias_r[3], 0.f);
            *(float4*)&C[(size_t)row * UNITS + block_n + tx * 4] = o;
        }
    }
}

extern "C" void kernel_launch(void* const* d_in, const int* in_sizes, int n_in,
                              void* d_out, int out_size, void* d_ws, size_t ws_size,
                              hipStream_t stream) {
    const int*   erow = (const int*)d_in[0];
    const int*   ecol = (const int*)d_in[1];
    const float* eval = (const float*)d_in[2];
    const float* x    = (const float*)d_in[3];
    const float* w    = (const float*)d_in[4];
    const float* bias = (const float*)d_in[5];
    float* out = (float*)d_out;

    // Workspace carve-up (all 16B-aligned offsets):
    //   tmp      : N_NODES*256 f32   = 102,400,000 B
    //   row_ptr  : N_NODES i32       =     400,000 B
    //   cnt      : N_NODES i32       =     400,000 B
    //   cursor   : N_NODES i32       =     400,000 B
    //   csum     : NCHUNKS i32 (pad) =       4,096 B
    //   col_val  : N_EDGES int2      =  25,600,000 B
    char* ws = (char*)d_ws;
    float* tmp     = (float*)(ws);
    int*   row_ptr = (int*)(ws + 102400000);
    int*   cnt     = (int*)(ws + 102400000 + 400000);
    int*   cursor  = (int*)(ws + 102400000 + 800000);
    int*   csum    = (int*)(ws + 102400000 + 1200000);
    int2*  col_val = (int2*)(ws + 102400000 + 1200000 + 4096);

    // --- CSR build (per launch; ws is re-poisoned before every call) ---
    hipMemsetAsync(cnt, 0, N_NODES * sizeof(int), stream);
    hist_rows<<<(N_EDGES + 255) / 256, 256, 0, stream>>>(erow, cnt);
    chunk_sums_k<<<NCHUNKS, 256, 0, stream>>>(cnt, csum);
    scan_chunk_sums<<<1, 64, 0, stream>>>(csum);
    scan_final<<<NCHUNKS, 256, 0, stream>>>(cnt, csum, row_ptr, cursor);
    fill_csr<<<(N_EDGES + 255) / 256, 256, 0, stream>>>(erow, ecol, eval, cursor, col_val);

    // --- tmp = A_coo @ X  (no float atomics, each row written once) ---
    gather_rows<<<(N_NODES + 3) / 4, 256, 0, stream>>>(row_ptr, cnt, col_val, x, tmp);

    // --- out = relu(tmp @ W + bias) ---
    dim3 grid((N_NODES + BM - 1) / BM, UNITS / BN);
    gemm_bias_relu<<<grid, 256, 0, stream>>>(tmp, w, bias, out, N_NODES);
}

// Round 3
// 872.749 us; speedup vs baseline: 12.4925x; 1.3480x over previous
//
#include <hip/hip_runtime.h>
#include <hip/hip_bf16.h>

#define N_NODES 100000
#define N_EDGES 3200000
#define DFEAT 256
#define UNITS 256

#define CHUNK 1024
#define NCHUNKS ((N_NODES + CHUNK - 1) / CHUNK)   // 98

typedef short bf16x8 __attribute__((ext_vector_type(8)));  // 8 bf16 (4 VGPRs), guide §3
typedef float f32x4 __attribute__((ext_vector_type(4)));

// RNE float -> bf16 bits
__device__ __forceinline__ unsigned short f2bf(float f) {
    union { float f; unsigned u; } v; v.f = f;
    unsigned u = v.u;
    u += 0x7FFFu + ((u >> 16) & 1u);
    return (unsigned short)(u >> 16);
}

// ---------------------------------------------------------------------------
// x (fp32, N x 256) -> xh (bf16). 1 float4 per thread.
// ---------------------------------------------------------------------------
__global__ __launch_bounds__(256) void convert_x(const float4* __restrict__ x4,
                                                 unsigned short* __restrict__ xh) {
    size_t i = (size_t)blockIdx.x * 256 + threadIdx.x;   // 6.4M float4s
    float4 v = x4[i];
    ushort4 o = make_ushort4(f2bf(v.x), f2bf(v.y), f2bf(v.z), f2bf(v.w));
    *(ushort4*)&xh[i * 4] = o;
}

// ---------------------------------------------------------------------------
// W (fp32, [k][n] 256x256) -> Wt (bf16, [n][k]) so GEMM B-fragments are
// contiguous along k in LDS. Tiny (65K elems).
// ---------------------------------------------------------------------------
__global__ void convert_w(const float* __restrict__ w, unsigned short* __restrict__ wt) {
    int n = blockIdx.x, k = threadIdx.x;
    wt[n * DFEAT + k] = f2bf(w[k * UNITS + n]);
}

// ---------------------------------------------------------------------------
// CSR build: histogram -> 2-level scan -> cursor scatter (int atomics only)
// ---------------------------------------------------------------------------
__global__ __launch_bounds__(256) void hist_rows(const int* __restrict__ erow,
                                                 int* __restrict__ cnt) {
    int e = blockIdx.x * 256 + threadIdx.x;
    if (e < N_EDGES) atomicAdd(&cnt[erow[e]], 1);
}

__global__ __launch_bounds__(256) void chunk_sums_k(const int* __restrict__ cnt,
                                                    int* __restrict__ csum) {
    __shared__ int red[256];
    int base = blockIdx.x * CHUNK;
    int s = 0;
    for (int i = threadIdx.x; i < CHUNK; i += 256) {
        int idx = base + i;
        s += (idx < N_NODES) ? cnt[idx] : 0;
    }
    red[threadIdx.x] = s;
    __syncthreads();
    for (int off = 128; off > 0; off >>= 1) {
        if (threadIdx.x < off) red[threadIdx.x] += red[threadIdx.x + off];
        __syncthreads();
    }
    if (threadIdx.x == 0) csum[blockIdx.x] = red[0];
}

__global__ void scan_chunk_sums(int* csum) {
    if (threadIdx.x == 0) {
        int run = 0;
        for (int i = 0; i < NCHUNKS; ++i) { int t = csum[i]; csum[i] = run; run += t; }
    }
}

__global__ __launch_bounds__(256) void scan_final(const int* __restrict__ cnt,
                                                  const int* __restrict__ csum,
                                                  int* __restrict__ row_ptr,
                                                  int* __restrict__ cursor) {
    __shared__ int tsum[256];
    const int tid = threadIdx.x;
    int base = blockIdx.x * CHUNK + tid * 4;
    int v[4];
#pragma unroll
    for (int j = 0; j < 4; ++j) {
        int idx = base + j;
        v[j] = (idx < N_NODES) ? cnt[idx] : 0;
    }
    int local = v[0] + v[1] + v[2] + v[3];
    tsum[tid] = local;
    __syncthreads();
    for (int off = 1; off < 256; off <<= 1) {
        int t = 0;
        if (tid >= off) t = tsum[tid - off];
        __syncthreads();
        if (tid >= off) tsum[tid] += t;
        __syncthreads();
    }
    int prefix = csum[blockIdx.x] + tsum[tid] - local;
#pragma unroll
    for (int j = 0; j < 4; ++j) {
        int idx = base + j;
        if (idx < N_NODES) { row_ptr[idx] = prefix; cursor[idx] = prefix; }
        prefix += v[j];
    }
}

// Packed edge record: col (17 bits) << 15 | bf16(val) low 15 bits (sign=0, val>=0)
__global__ __launch_bounds__(256) void fill_csr(const int* __restrict__ erow,
                                                const int* __restrict__ ecol,
                                                const float* __restrict__ eval,
                                                int* __restrict__ cursor,
                                                unsigned* __restrict__ cv) {
    int e = blockIdx.x * 256 + threadIdx.x;
    if (e >= N_EDGES) return;
    int r = erow[e];
    int pos = atomicAdd(&cursor[r], 1);
    cv[pos] = (((unsigned)ecol[e]) << 15) | (f2bf(eval[e]) & 0x7FFFu);
}

// ---------------------------------------------------------------------------
// Aggregate: one wave per row, bf16 x gather (8 B/lane), fp32 accumulate,
// bf16 tmp write. Zero float atomics.
// ---------------------------------------------------------------------------
__global__ __launch_bounds__(256) void gather_rows(const int* __restrict__ row_ptr,
                                                   const int* __restrict__ cnt,
                                                   const unsigned* __restrict__ cv,
                                                   const unsigned short* __restrict__ xh,
                                                   unsigned short* __restrict__ tmp) {
    const int row = blockIdx.x * 4 + (threadIdx.x >> 6);
    if (row >= N_NODES) return;
    const int lane = threadIdx.x & 63;
    const int start = row_ptr[row];
    const int deg = cnt[row];
    const unsigned* __restrict__ p = cv + start;
    const uint2* __restrict__ x2 = (const uint2*)xh;   // row = 64 x uint2 (4 bf16 each)

    float a0 = 0.f, a1 = 0.f, a2 = 0.f, a3 = 0.f;
    int i = 0;
    for (; i + 1 < deg; i += 2) {
        unsigned e0 = p[i], e1 = p[i + 1];
        uint2 g0 = x2[(size_t)(e0 >> 15) * 64 + lane];
        uint2 g1 = x2[(size_t)(e1 >> 15) * 64 + lane];
        float v0 = __uint_as_float((e0 & 0x7FFFu) << 16);
        float v1 = __uint_as_float((e1 & 0x7FFFu) << 16);
        a0 = fmaf(v0, __uint_as_float(g0.x << 16), a0);
        a1 = fmaf(v0, __uint_as_float(g0.x & 0xFFFF0000u), a1);
        a2 = fmaf(v0, __uint_as_float(g0.y << 16), a2);
        a3 = fmaf(v0, __uint_as_float(g0.y & 0xFFFF0000u), a3);
        a0 = fmaf(v1, __uint_as_float(g1.x << 16), a0);
        a1 = fmaf(v1, __uint_as_float(g1.x & 0xFFFF0000u), a1);
        a2 = fmaf(v1, __uint_as_float(g1.y << 16), a2);
        a3 = fmaf(v1, __uint_as_float(g1.y & 0xFFFF0000u), a3);
    }
    if (i < deg) {
        unsigned e0 = p[i];
        uint2 g0 = x2[(size_t)(e0 >> 15) * 64 + lane];
        float v0 = __uint_as_float((e0 & 0x7FFFu) << 16);
        a0 = fmaf(v0, __uint_as_float(g0.x << 16), a0);
        a1 = fmaf(v0, __uint_as_float(g0.x & 0xFFFF0000u), a1);
        a2 = fmaf(v0, __uint_as_float(g0.y << 16), a2);
        a3 = fmaf(v0, __uint_as_float(g0.y & 0xFFFF0000u), a3);
    }
    ushort4 o = make_ushort4(f2bf(a0), f2bf(a1), f2bf(a2), f2bf(a3));
    *(ushort4*)&tmp[(size_t)row * 256 + lane * 4] = o;
}

// ---------------------------------------------------------------------------
// out = relu(tmp @ W + bias) via bf16 MFMA 16x16x32.
// 128x128 block, 4 waves (2m x 2n), each wave 64x64 = 4x4 tiles of 16x16.
// As/Bs rows padded to 72 bf16 (16B pad) -> frag reads are 2-way max (free).
// Fragment layout (m89-verified): A m=lane&15, k=quad*8+j; C/D col=lane&15,
// row=quad*4+reg.
// ---------------------------------------------------------------------------
#define GBM 128
#define GBN 128
#define GBK 64
#define LDK 72

__global__ __launch_bounds__(256) void gemm_mfma(
    const unsigned short* __restrict__ A,    // tmp bf16 [M][256]
    const unsigned short* __restrict__ Bt,   // Wt bf16 [N][K] = [256][256]
    const float* __restrict__ bias,
    float* __restrict__ C, int M)
{
    __shared__ unsigned short As[GBM * LDK];
    __shared__ unsigned short Bs[GBN * LDK];

    const int tid = threadIdx.x;
    const int lane = tid & 63;
    const int wid = tid >> 6;
    const int wave_m = wid & 1, wave_n = wid >> 1;
    const int block_m = blockIdx.x * GBM;
    const int block_n = blockIdx.y * GBN;

    const int r = tid >> 1;        // staging row 0..127
    const int half = tid & 1;      // which 32-elem half of the 64-wide k-chunk

    const int quad = lane >> 4;
    const int l16 = lane & 15;

    f32x4 acc[4][4];
#pragma unroll
    for (int i = 0; i < 4; ++i)
#pragma unroll
        for (int j = 0; j < 4; ++j)
            acc[i][j] = {0.f, 0.f, 0.f, 0.f};

    for (int k0 = 0; k0 < DFEAT; k0 += GBK) {
        // --- stage A tile (guarded) ---
        {
            const int gm = block_m + r;
            uint4 v[4] = {};
            if (gm < M) {
                const uint4* src = (const uint4*)(A + (size_t)gm * DFEAT + k0 + half * 32);
                v[0] = src[0]; v[1] = src[1]; v[2] = src[2]; v[3] = src[3];
            }
            uint4* dst = (uint4*)&As[r * LDK + half * 32];
            dst[0] = v[0]; dst[1] = v[1]; dst[2] = v[2]; dst[3] = v[3];
        }
        // --- stage B tile (N=256 exact, no guard) ---
        {
            const uint4* src = (const uint4*)(Bt + (size_t)(block_n + r) * DFEAT + k0 + half * 32);
            uint4* dst = (uint4*)&Bs[r * LDK + half * 32];
            dst[0] = src[0]; dst[1] = src[1]; dst[2] = src[2]; dst[3] = src[3];
        }
        __syncthreads();

#pragma unroll
        for (int kc = 0; kc < 2; ++kc) {
            const int ko = kc * 32 + quad * 8;
            bf16x8 af[4], bfr[4];
#pragma unroll
            for (int i = 0; i < 4; ++i)
                af[i] = *(const bf16x8*)&As[(wave_m * 64 + i * 16 + l16) * LDK + ko];
#pragma unroll
            for (int j = 0; j < 4; ++j)
                bfr[j] = *(const bf16x8*)&Bs[(wave_n * 64 + j * 16 + l16) * LDK + ko];
#pragma unroll
            for (int i = 0; i < 4; ++i)
#pragma unroll
                for (int j = 0; j < 4; ++j)
                    acc[i][j] = __builtin_amdgcn_mfma_f32_16x16x32_bf16(
                        af[i], bfr[j], acc[i][j], 0, 0, 0);
        }
        __syncthreads();
    }

    // epilogue: bias + relu
#pragma unroll
    for (int j = 0; j < 4; ++j) {
        const int n = block_n + wave_n * 64 + j * 16 + l16;
        const float bj = bias[n];
#pragma unroll
        for (int i = 0; i < 4; ++i) {
            const int m0 = block_m + wave_m * 64 + i * 16 + quad * 4;
#pragma unroll
            for (int rg = 0; rg < 4; ++rg) {
                const int m = m0 + rg;
                if (m < M)
                    C[(size_t)m * UNITS + n] = fmaxf(acc[i][j][rg] + bj, 0.f);
            }
        }
    }
}

extern "C" void kernel_launch(void* const* d_in, const int* in_sizes, int n_in,
                              void* d_out, int out_size, void* d_ws, size_t ws_size,
                              hipStream_t stream) {
    const int*   erow = (const int*)d_in[0];
    const int*   ecol = (const int*)d_in[1];
    const float* eval = (const float*)d_in[2];
    const float* x    = (const float*)d_in[3];
    const float* w    = (const float*)d_in[4];
    const float* bias = (const float*)d_in[5];
    float* out = (float*)d_out;

    // Workspace carve-up (bytes, all 16B-aligned):
    //   tmp bf16  : 100000*256*2 = 51,200,000
    //   row_ptr   : 400,000
    //   cnt       : 400,000
    //   cursor    : 400,000
    //   csum      : 4,096
    //   cv (u32)  : 12,800,000
    //   Wt bf16   : 131,072          total ~65.3 MB (R2 proved ws >= 129 MB)
    char* ws = (char*)d_ws;
    unsigned short* tmp     = (unsigned short*)(ws);
    int*            row_ptr = (int*)(ws + 51200000);
    int*            cnt     = (int*)(ws + 51600000);
    int*            cursor  = (int*)(ws + 52000000);
    int*            csum    = (int*)(ws + 52400000);
    unsigned*       cv      = (unsigned*)(ws + 52404096);
    unsigned short* wt      = (unsigned short*)(ws + 65204096);

    // xh (bf16 x, 51.2 MB) lives in d_out's buffer — dead before gemm writes out.
    unsigned short* xh = (unsigned short*)d_out;

    // dtype converts (independent of CSR build)
    convert_x<<<(N_NODES * DFEAT / 4) / 256, 256, 0, stream>>>((const float4*)x, xh);
    convert_w<<<UNITS, DFEAT, 0, stream>>>(w, wt);

    // CSR build (int atomics only)
    hipMemsetAsync(cnt, 0, N_NODES * sizeof(int), stream);
    hist_rows<<<(N_EDGES + 255) / 256, 256, 0, stream>>>(erow, cnt);
    chunk_sums_k<<<NCHUNKS, 256, 0, stream>>>(cnt, csum);
    scan_chunk_sums<<<1, 64, 0, stream>>>(csum);
    scan_final<<<NCHUNKS, 256, 0, stream>>>(cnt, csum, row_ptr, cursor);
    fill_csr<<<(N_EDGES + 255) / 256, 256, 0, stream>>>(erow, ecol, eval, cursor, cv);

    // tmp = A_coo @ X (bf16 in / fp32 acc / bf16 out)
    gather_rows<<<(N_NODES + 3) / 4, 256, 0, stream>>>(row_ptr, cnt, cv, xh, tmp);

    // out = relu(tmp @ W + bias) via bf16 MFMA
    dim3 grid((N_NODES + GBM - 1) / GBM, UNITS / GBN);
    gemm_mfma<<<grid, 256, 0, stream>>>(tmp, wt, bias, out, N_NODES);
}